// Round 7
// baseline (255.534 us; speedup 1.0000x reference)
//
#include <hip/hip_runtime.h>
#include <hip/hip_bf16.h>

// ---------------------------------------------------------------------------
// OuterProductMean (AlphaFold) fused MFMA implementation for gfx950.
//   B=1, N=128 (MSA depth), L=256, C_M=256, C_H=32, C_Z=128
// Pipeline (3 launches):
//   k_prep    : all weight prep: WT bf16 [64][256]; W2 = Wo bf16
//               fragment-sequential (zg,s,r16,kg,e); pm_recip.
//   k_ln_proj : LayerNorm + a/b projection (MFMA) -> aT/bT bf16 [8192][128]
//               (row = l*32+h, col = MSA index n -> K-contiguous operand rows).
//   k_outer   : 512 thr / 8 waves, 32KB LDS (O2b only). Stage-1 fragments are
//               loaded DIRECTLY from global (L2-resident aT/bT) — R6 showed
//               the LDS pipe ~60% occupied by staging+reads while MFMA sat at
//               15%; removing staging halves LDS traffic and drops 2 barriers.
//               Then transpose accs -> bf16 A-fragment layout in LDS, stage-2
//               [16,1024]@Wo[1024,128] GEMM, scale+bias epilogue.
// ---------------------------------------------------------------------------

typedef __attribute__((ext_vector_type(8))) short bf8_t;   // 8 x bf16 (4 VGPRs)
typedef __attribute__((ext_vector_type(4))) float f32x4;   // MFMA accumulator

__device__ __forceinline__ unsigned short f2bf(float f) {
    unsigned int u = __float_as_uint(f);
    u += 0x7fffu + ((u >> 16) & 1u);        // RNE (finite values only)
    return (unsigned short)(u >> 16);
}
__device__ __forceinline__ unsigned int pack2(float a, float b) {
    return (unsigned int)f2bf(a) | ((unsigned int)f2bf(b) << 16);
}

// ---------------------------------------------------------------------------
// Blocks [0,64): WT[h][c] = (h<32 ? Wa[c][h] : Wb[c][h-32]).
// Blocks [64,576): W2 fragment-sequential transpose of Wo.
// Blocks [576,832): pm_recip[i,j] = 1/(sum_n mask[n,i]*mask[n,j] + 1e-8).
__global__ __launch_bounds__(256) void k_prep(
    const float* __restrict__ Wa, const float* __restrict__ Wb,
    const float* __restrict__ Wo, const float* __restrict__ gmask,
    unsigned short* __restrict__ WTb, unsigned short* __restrict__ W2,
    float* __restrict__ pmr)
{
    const int tid = threadIdx.x;
    int b = blockIdx.x;
    if (b < 64) {
        int u = b * 256 + tid;                       // u = h*256 + c
        int h = u >> 8, c = u & 255;
        float v = (h < 32) ? Wa[c * 32 + h] : Wb[c * 32 + (h - 32)];
        WTb[u] = f2bf(v);
    } else if (b < 576) {
        // W2: (zg=z>>4, s=k'>>5, r16=z&15, kg=(k'>>3)&3, e=k'&7), k' = d*32+c
        int u = (b - 64) * 256 + tid;                // u = k*128 + z (coalesced read)
        int k = u >> 7, z = u & 127;
        int c = k >> 5, d = k & 31;
        int kp = d * 32 + c;
        int dst = (((z >> 4) * 32 + (kp >> 5)) * 16 + (z & 15)) * 32
                  + ((kp >> 3) & 3) * 8 + (kp & 7);
        W2[dst] = f2bf(Wo[u]);
    } else {
        int u = (b - 576) * 256 + tid;               // u = i*256 + j
        int i = u >> 8, j = u & 255;
        float s = 0.f;
        #pragma unroll 8
        for (int n = 0; n < 128; n++)
            s += gmask[n * 256 + i] * gmask[n * 256 + j];
        pmr[u] = 1.f / (s + 1e-8f);
    }
}

// ---------------------------------------------------------------------------
// LayerNorm + projection. 2048 blocks; block = 256 thr (4 waves), 16 MSA rows
// (n0..n0+15) at fixed l.
__global__ __launch_bounds__(256) void k_ln_proj(
    const float* __restrict__ gm, const float* __restrict__ gmask,
    const float* __restrict__ gamma, const float* __restrict__ beta,
    const unsigned short* __restrict__ WTb,
    const float* __restrict__ ba, const float* __restrict__ bb,
    unsigned short* __restrict__ aT, unsigned short* __restrict__ bT)
{
    __shared__ __align__(16) unsigned short xlb[16 * 256]; // [row][c] bf16, swizzled
    __shared__ float vl[16 * 64];                          // [n-row][h]
    const int tid = threadIdx.x;
    const int lane = tid & 63, w = tid >> 6;
    const int l = blockIdx.x & 255, n0 = ((int)blockIdx.x >> 8) << 4;

    const float4 g4  = ((const float4*)gamma)[lane];
    const float4 be4 = ((const float4*)beta)[lane];

    // ---- phase 1: LN (wave per row, 4 rows per wave) ----
    #pragma unroll
    for (int j = 0; j < 4; j++) {
        int row = w * 4 + j;
        int n = n0 + row;
        float4 v = ((const float4*)(gm + ((size_t)n * 256 + l) * 256))[lane];
        float s = v.x + v.y + v.z + v.w;
        float q = v.x * v.x + v.y * v.y + v.z * v.z + v.w * v.w;
        #pragma unroll
        for (int off = 1; off < 64; off <<= 1) {
            s += __shfl_xor(s, off);
            q += __shfl_xor(q, off);
        }
        float mean = s * (1.f / 256.f);
        float var = fmaxf(q * (1.f / 256.f) - mean * mean, 0.f);
        float rstd = rsqrtf(var + 1e-5f);
        float x0 = (v.x - mean) * rstd * g4.x + be4.x;
        float x1 = (v.y - mean) * rstd * g4.y + be4.y;
        float x2 = (v.z - mean) * rstd * g4.z + be4.z;
        float x3 = (v.w - mean) * rstd * g4.w + be4.w;
        int c8s = lane ^ ((row & 7) << 1);               // 8B-chunk XOR swizzle
        *(uint2*)((char*)xlb + row * 512 + (c8s << 3)) =
            make_uint2(pack2(x0, x1), pack2(x2, x3));
    }
    __syncthreads();

    // ---- phase 2: projection via MFMA (wave w -> h-cols w*16..w*16+15) ----
    const int kg = lane >> 4, r16 = lane & 15;
    const int h = w * 16 + r16;
    f32x4 acc = {0.f, 0.f, 0.f, 0.f};
    #pragma unroll
    for (int ks = 0; ks < 8; ks++) {
        int c8 = ks * 8 + kg * 2;                        // even -> 16B pair intact
        bf8_t af = *(const bf8_t*)((char*)xlb + r16 * 512 +
                                   ((c8 ^ ((r16 & 7) << 1)) << 3));
        bf8_t wf = *(const bf8_t*)(WTb + (size_t)h * 256 + ks * 32 + kg * 8);
        acc = __builtin_amdgcn_mfma_f32_16x16x32_bf16(af, wf, acc, 0, 0, 0);
    }
    float bias = (h < 32) ? ba[h] : bb[h - 32];
    #pragma unroll
    for (int r = 0; r < 4; r++) {
        int nrow = kg * 4 + r;                           // C/D row = MSA row index
        float mk = gmask[(size_t)(n0 + nrow) * 256 + l];
        vl[nrow * 64 + h] = (acc[r] + bias) * mk;
    }
    __syncthreads();

    // ---- phase 3: repack, 8 n-values per thread, 16B stores ----
    if (tid < 128) {
        int row = tid >> 1, half = tid & 1;              // row = h index 0..63
        int hh = row & 31;
        unsigned short* dst = (row < 32) ? aT : bT;
        unsigned int pk[4];
        #pragma unroll
        for (int jj = 0; jj < 4; jj++)
            pk[jj] = pack2(vl[(half * 8 + 2 * jj) * 64 + row],
                           vl[(half * 8 + 2 * jj + 1) * 64 + row]);
        *(uint4*)(dst + ((size_t)l * 32 + hh) * 128 + n0 + half * 8) =
            make_uint4(pk[0], pk[1], pk[2], pk[3]);
    }
}

// ---------------------------------------------------------------------------
// Fused outer-product + Wo projection. 512 thr = 8 waves; 32KB LDS (O2b only).
// Grid 4096 = 64 tj (fast) x 64 ti. Wave quadrant: wr(2) x wc(4) -> 64x32.
// Stage-1 A/B fragments loaded directly from global (L2-resident).
__global__ __launch_bounds__(512) void k_outer(
    const unsigned short* __restrict__ aT, const unsigned short* __restrict__ bT,
    const unsigned short* __restrict__ W2, const float* __restrict__ pmr,
    const float* __restrict__ bo, float* __restrict__ out)
{
    __shared__ __align__(16) char smem[32768];
    const int tid = threadIdx.x, lane = tid & 63, w = tid >> 6;   // 8 waves
    const int wr = w >> 2, wc = w & 3;
    const int tj = blockIdx.x & 63, ti = blockIdx.x >> 6;
    const int kg = lane >> 4, r16 = lane & 15;

    f32x4 acc[4][2];
    #pragma unroll
    for (int mt = 0; mt < 4; mt++)
        #pragma unroll
        for (int nt = 0; nt < 2; nt++)
            acc[mt][nt] = (f32x4){0.f, 0.f, 0.f, 0.f};

    // ---- stage 1: 128x128 outer tile, fragments straight from global ----
    // lane (kg,r16) reads 16B at row (.. + r16), cols kg*8 + ks*32 -> the wave
    // touches 16 rows x 64B contiguous segments; all L2-hot.
    const unsigned short* Abase = aT + ((size_t)(ti * 128 + wr * 64 + r16)) * 128 + kg * 8;
    const unsigned short* Bbase = bT + ((size_t)(tj * 128 + wc * 32 + r16)) * 128 + kg * 8;
    #pragma unroll
    for (int ks = 0; ks < 4; ks++) {
        bf8_t af[4], bfr[2];
        #pragma unroll
        for (int mt = 0; mt < 4; mt++)
            af[mt] = *(const bf8_t*)(Abase + mt * 16 * 128 + ks * 32);
        #pragma unroll
        for (int nt = 0; nt < 2; nt++)
            bfr[nt] = *(const bf8_t*)(Bbase + nt * 16 * 128 + ks * 32);
        #pragma unroll
        for (int mt = 0; mt < 4; mt++)
            #pragma unroll
            for (int nt = 0; nt < 2; nt++)
                acc[mt][nt] = __builtin_amdgcn_mfma_f32_16x16x32_bf16(
                    af[mt], bfr[nt], acc[mt][nt], 0, 0, 0);
    }

    // ---- transpose accs -> O2b[p][k2] bf16 in LDS, A-fragment order ----
    // k2 = (nn&31)*32 + (mm&31); chunk c2=k2>>3; swizzle spreads writer lanes
    // over all 8 bank groups: pc = c2 ^ ((c2>>3)&7) ^ (p&7).
    unsigned short* O2b = (unsigned short*)smem;        // 16 x 1024 bf16 = 32 KB
    #pragma unroll
    for (int mt = 0; mt < 4; mt++) {
        int mmb = wr * 64 + mt * 16 + kg * 4;           // + r (r stays in-chunk)
        #pragma unroll
        for (int nt = 0; nt < 2; nt++) {
            int nn = wc * 32 + nt * 16 + r16;
            int p  = ((mmb >> 5) << 2) | (nn >> 5);     // pair = i_loc*4 + j_loc
            int k2 = ((nn & 31) << 5) | (mmb & 31);
            int c2 = k2 >> 3;
            int pc = c2 ^ ((c2 >> 3) & 7) ^ (p & 7);
            *(uint2*)(O2b + p * 1024 + pc * 8 + (k2 & 7)) =
                make_uint2(pack2(acc[mt][nt][0], acc[mt][nt][1]),
                           pack2(acc[mt][nt][2], acc[mt][nt][3]));
        }
    }
    __syncthreads();

    // ---- stage 2: Z[16 pairs, 128] = O2[16,1024] @ Wo[1024,128] ----
    // Wave w handles z in [w*16, w*16+16): reads its 32KB slice of W2 once.
    f32x4 acc2 = {0.f, 0.f, 0.f, 0.f};
    const unsigned short* O2r = O2b + r16 * 1024;        // A-operand row = pair
    const int psw = r16 & 7;
    const unsigned short* wz = W2 + (size_t)w * 16384 + r16 * 32 + kg * 8;
    #pragma unroll 8
    for (int s = 0; s < 32; s++) {
        int c2 = s * 4 + kg;
        int pc = c2 ^ ((c2 >> 3) & 7) ^ psw;
        bf8_t av = *(const bf8_t*)(O2r + pc * 8);
        bf8_t wf = *(const bf8_t*)(wz + s * 512);
        acc2 = __builtin_amdgcn_mfma_f32_16x16x32_bf16(av, wf, acc2, 0, 0, 0);
    }

    // ---- epilogue: scale by 1/(pair_mask+eps), add bias, store ----
    const int i0 = ti * 4, j0 = tj * 4;
    const int z = w * 16 + r16;
    const float boz = bo[z];
    #pragma unroll
    for (int r = 0; r < 4; r++) {
        int p = kg * 4 + r;
        int i = i0 + (p >> 2), j = j0 + (p & 3);
        float recip = pmr[i * 256 + j];
        out[((size_t)(i * 256 + j)) * 128 + z] = acc2[r] * recip + boz;
    }
}

// ---------------------------------------------------------------------------
extern "C" void kernel_launch(void* const* d_in, const int* in_sizes, int n_in,
                              void* d_out, int out_size, void* d_ws, size_t ws_size,
                              hipStream_t stream)
{
    const float* m    = (const float*)d_in[0];
    const float* mask = (const float*)d_in[1];
    const float* gam  = (const float*)d_in[2];
    const float* bet  = (const float*)d_in[3];
    const float* Wa   = (const float*)d_in[4];
    const float* ba   = (const float*)d_in[5];
    const float* Wb   = (const float*)d_in[6];
    const float* bb   = (const float*)d_in[7];
    const float* Wo   = (const float*)d_in[8];
    const float* bo   = (const float*)d_in[9];
    float* out = (float*)d_out;

    unsigned short* aT  = (unsigned short*)d_ws;           // 8192*128 bf16 = 2 MB
    unsigned short* bT  = aT + 8192 * 128;                 // 2 MB
    unsigned short* W2  = bT + 8192 * 128;                 // 128*1024 bf16 = 256 KB
    unsigned short* WTb = W2 + 128 * 1024;                 // 64*256 bf16 = 32 KB
    float* pmr = (float*)(WTb + 64 * 256);                 // 256*256 fp32 = 256 KB

    k_prep   <<< 832, 256, 0, stream>>>(Wa, Wb, Wo, mask, WTb, W2, pmr);
    k_ln_proj<<<2048, 256, 0, stream>>>(m, mask, gam, bet, WTb, ba, bb, aT, bT);
    k_outer  <<<4096, 512, 0, stream>>>(aT, bT, W2, pmr, bo, out);
}